// Round 4
// baseline (439.201 us; speedup 1.0000x reference)
//
#include <hip/hip_runtime.h>
#include <hip/hip_bf16.h>

// MoE top-2, d=1024, E=8, N=8192 tokens. Grouped-GEMM design:
//   gate(top2 + x->bf16 cast + zeroing) -> fillplan -> GEMM1(relu) -> GEMM2(+atomic combine)
// R4-R7 post-mortem: 128^2 2-phase lockstep family is stuck at 11-12% MfmaUtil across
//   all knobs (buffer depth, BK, conflicts=0) -> structural 2-phase stall (m233).
// R8: 256^2 4-phase-per-K-tile schedule (T3+T4+T5, m201/m248 lineage):
//   512 thr = 8 waves (2M x 4N), per-wave 128x64 out, BK=64, LDS 128KB (2 dbuf).
//   Per K-tile: 4 phases {ds_read subtile || stage half-tile -> barrier -> lgkm(0)
//   -> setprio(1) 16 MFMA setprio(0) -> barrier}; counted vmcnt(4) once per K-tile
//   (loads for next K-tile stay in flight across barriers; never drain in loop).
//   Staging keeps R7's verified conflict-free 8-seg XOR swizzle; fences per R6.
//   Expert padding 256; grid 288 = 4 col x 72 row tiles, XCD-swizzled.

#define NTOK   8192
#define DM     1024
#define NE     8
#define BM     256
#define NSLOT  (NTOK * 2)
#define PADCAP (NSLOT + NE * BM)      // 18432
#define MAXTILES (PADCAP / BM)        // 72

typedef __attribute__((ext_vector_type(8))) short  bf16x8;
typedef __attribute__((ext_vector_type(4))) float  f32x4;
typedef __attribute__((ext_vector_type(8))) unsigned short u16x8;

__device__ __forceinline__ unsigned short f2bf(float f) {
    union { float f; unsigned u; } v; v.f = f;
    unsigned r = v.u + 0x7fffu + ((v.u >> 16) & 1u);
    return (unsigned short)(r >> 16);
}

// async global->LDS DMA, 16B per lane; dest = wave-uniform base + lane*16
__device__ __forceinline__ void load_lds16(const ushort* g, ushort* l) {
    __builtin_amdgcn_global_load_lds(
        (const __attribute__((address_space(1))) unsigned int*)g,
        (__attribute__((address_space(3))) unsigned int*)l,
        16, 0, 0);
}

// ---------- transpose + cast both weight tensors: Wt[e][n][k] = W[e][k][n] ----------
// Also zeroes counts/cursor (runs first on the stream; k_gate depends on it).
__global__ __launch_bounds__(256) void k_transpose2(const float* __restrict__ W1,
                                                    const float* __restrict__ W2,
                                                    ushort* __restrict__ w1t,
                                                    ushort* __restrict__ w2t,
                                                    int* __restrict__ counts) {
    int tid = threadIdx.x;
    if (blockIdx.x == 0 && blockIdx.y == 0 && blockIdx.z == 0 && tid < 16)
        counts[tid] = 0;   // counts[0..7] + cursor[0..7]
    int ez = blockIdx.z;
    const float* W = (ez < 8 ? W1 : W2) + (size_t)(ez & 7) * DM * DM;
    ushort* Wt = (ez < 8 ? w1t : w2t) + (size_t)(ez & 7) * DM * DM;
    __shared__ float t[64][65];
    int kt = blockIdx.y * 64, nt = blockIdx.x * 64;
    int r16 = tid >> 4, c4 = (tid & 15) * 4;
#pragma unroll
    for (int p = 0; p < 4; p++) {
        int k = p * 16 + r16;
        float4 v = *(const float4*)&W[(size_t)(kt + k) * DM + nt + c4];
        t[k][c4] = v.x; t[k][c4 + 1] = v.y; t[k][c4 + 2] = v.z; t[k][c4 + 3] = v.w;
    }
    __syncthreads();
    int n = tid >> 2, kb = (tid & 3) * 16;
#pragma unroll
    for (int h = 0; h < 2; h++) {
        int k0 = kb + h * 8;
        u16x8 o;
#pragma unroll
        for (int i = 0; i < 8; i++) o[i] = f2bf(t[k0 + i][n]);
        *(u16x8*)&Wt[(size_t)(nt + n) * DM + kt + k0] = o;
    }
}

// ---------- gating: scores = x@Wg + bg (fp32 exact), top-2, counts; casts x->bf16 ----------
// Also zeroes its 16 output rows and its slot_token chunk (replaces memset launches).
__global__ __launch_bounds__(256) void k_gate(const float* __restrict__ x,
                                              const float* __restrict__ Wg,
                                              const float* __restrict__ bg,
                                              ushort* __restrict__ xb,
                                              int* __restrict__ tok_e,
                                              float* __restrict__ tok_w,
                                              int* __restrict__ counts,
                                              float* __restrict__ out,
                                              int* __restrict__ slot_token) {
    __shared__ float wgT[NE][DM];   // 32 KB, transposed: wgT[e][d] = Wg[d][e]
    __shared__ int cnt[NE];
    int tid = threadIdx.x;
    if (tid < NE) cnt[tid] = 0;
    // zero out rows [16*blk, 16*blk+16): 4096 float4 across 256 threads
    {
        float4 z4 = {0.f, 0.f, 0.f, 0.f};
        float4* orow = (float4*)(out + (size_t)blockIdx.x * 16 * DM);
#pragma unroll
        for (int i = 0; i < 16; i++) orow[i * 256 + tid] = z4;
        // slot_token sentinels: PADCAP = 512 blocks * 36
        int s0 = blockIdx.x * (PADCAP / 512);
        for (int i = tid; i < PADCAP / 512; i += 256) slot_token[s0 + i] = -1;
    }
    for (int i = tid; i < DM * NE; i += 256) {
        int d = i >> 3, e = i & 7;
        wgT[e][d] = Wg[i];
    }
    __syncthreads();
    int wave = tid >> 6, lane = tid & 63;
    int n0 = (blockIdx.x * 4 + wave) * 4;
    const float4* xr[4];
#pragma unroll
    for (int t = 0; t < 4; t++) xr[t] = (const float4*)(x + (size_t)(n0 + t) * DM);

    float acc[4][NE];
#pragma unroll
    for (int t = 0; t < 4; t++)
#pragma unroll
        for (int e = 0; e < NE; e++) acc[t][e] = 0.f;

#pragma unroll
    for (int j = 0; j < 4; j++) {
        float4 xv[4];
#pragma unroll
        for (int t = 0; t < 4; t++) xv[t] = xr[t][j * 64 + lane];
#pragma unroll
        for (int t = 0; t < 4; t++) {
            ushort4 o;
            o.x = f2bf(xv[t].x); o.y = f2bf(xv[t].y);
            o.z = f2bf(xv[t].z); o.w = f2bf(xv[t].w);
            ((ushort4*)xb)[(size_t)(n0 + t) * (DM / 4) + j * 64 + lane] = o;
        }
#pragma unroll
        for (int e = 0; e < NE; e++) {
            float4 wv = ((const float4*)&wgT[e][0])[j * 64 + lane];
#pragma unroll
            for (int t = 0; t < 4; t++) {
                acc[t][e] += xv[t].x * wv.x + xv[t].y * wv.y
                           + xv[t].z * wv.z + xv[t].w * wv.w;
            }
        }
    }
#pragma unroll
    for (int t = 0; t < 4; t++)
#pragma unroll
        for (int e = 0; e < NE; e++) {
#pragma unroll
            for (int off = 32; off >= 1; off >>= 1)
                acc[t][e] += __shfl_xor(acc[t][e], off);
        }
    if (lane < 4) {
        int t = lane, n = n0 + t;
        float sc[NE];
#pragma unroll
        for (int e = 0; e < NE; e++) sc[e] = acc[t][e] + bg[e];
        int e0 = 0; float v0 = sc[0];
#pragma unroll
        for (int e = 1; e < NE; e++) if (sc[e] > v0) { v0 = sc[e]; e0 = e; }
        int e1 = -1; float v1 = -3.0e38f;
#pragma unroll
        for (int e = 0; e < NE; e++) if (e != e0 && sc[e] > v1) { v1 = sc[e]; e1 = e; }
        tok_e[2 * n] = e0;     tok_w[2 * n] = v0;
        tok_e[2 * n + 1] = e1; tok_w[2 * n + 1] = v1;
        atomicAdd(&cnt[e0], 1);
        atomicAdd(&cnt[e1], 1);
    }
    __syncthreads();
    if (tid < NE) atomicAdd(&counts[tid], cnt[tid]);
}

// ---------- fill + plan merged: per-thread local base; block 0 writes tile tables ----------
__global__ __launch_bounds__(256) void k_fillplan(const int* __restrict__ tok_e,
                                                  const float* __restrict__ tok_w,
                                                  const int* __restrict__ counts,
                                                  int* __restrict__ cursor,
                                                  int* __restrict__ slot_token,
                                                  float* __restrict__ slot_w,
                                                  int* __restrict__ tile_e,
                                                  int* __restrict__ tile_b,
                                                  int* __restrict__ ntiles) {
    int tid = threadIdx.x;
    int cnts[NE];
#pragma unroll
    for (int e = 0; e < NE; e++) cnts[e] = counts[e];
    int base[NE]; int off = 0;
#pragma unroll
    for (int e = 0; e < NE; e++) {
        base[e] = off;
        off += ((cnts[e] + BM - 1) / BM) * BM;
    }
    if (blockIdx.x == 0 && tid == 0) {
        int t = 0, o2 = 0;
        for (int e = 0; e < NE; e++) {
            int nt = (cnts[e] + BM - 1) / BM;
            for (int i = 0; i < nt; i++) { tile_e[t] = e; tile_b[t] = o2 + i * BM; t++; }
            o2 += nt * BM;
        }
        *ntiles = t;
    }
    int n = blockIdx.x * 256 + tid;
#pragma unroll
    for (int k = 0; k < 2; k++) {
        int e = tok_e[2 * n + k];
        float w = tok_w[2 * n + k];
        int pos = atomicAdd(&cursor[e], 1);
        int s = base[e] + pos;
        slot_token[s] = n;
        slot_w[s] = w;
    }
}

// ---------- grouped GEMM: 256x256 tile, BK=64, 4-phase K-tile schedule ----------
// 8 waves (wm=wave>>2 in {0,1}, wn=wave&3 in 0..3); per-wave output 128x64.
// LDS per operand: [buf2][256 rows][64 k] bf16 = 64KB; A+B = 128KB (1 block/CU).
// Row layout: element (row, k=g*8+i) at seg g^(row&7), byte = row*128 + seg*16.
// Staging: chunk = 8 rows x 128B = 1KB/instr; wave w stages rows 16w..16w+15 of each
//   128-row half-tile (2 instr per half per wave). Global seg = (l&7)^(l>>3) (R7-verified).
// Fragment read: sel = (ks*4+quad)^(lm&7) -> 8-lane groups cover all 8 segs ->
//   conflict-free ds_read_b128 (R7 measured 0 conflicts).
// Per K-tile (computes buf c, stages K-tile kt+1 into buf c^1):
//   top: stage A-h0,A-h1 (4 instr) -> s_waitcnt vmcnt(4) [kt's 8 retired, 4 in flight]
//        -> barrier -> sched_barrier
//   P0: read af(M0-3,ks01)=8 + bf(N0-1)=4; stage B-h0; bar; lgkm0; SB; prio1 16xMFMA prio0; SB; bar
//   P1: read bf(N2-3)=4;               stage B-h1; bar; lgkm0; SB; prio1 16xMFMA prio0; SB; bar
//   P2: read af(M4-7)=8;                           bar; lgkm0; SB; prio1 16xMFMA prio0; SB; bar
//   P3: prio1 16xMFMA prio0; SB
// vmcnt never drains to 0 in the main loop (T4); per-phase lgkm0 retires all reads of
// buf c before the phase-end barrier, so re-staging buf c next iteration is safe.
template <int PHASE>
__global__ __launch_bounds__(512) void k_gemm(const ushort* __restrict__ A,
                                              const ushort* __restrict__ Wt,
                                              const float* __restrict__ bias,
                                              const int* __restrict__ slot_token,
                                              const float* __restrict__ slot_w,
                                              const int* __restrict__ tile_e,
                                              const int* __restrict__ tile_b,
                                              const int* __restrict__ ntiles,
                                              ushort* __restrict__ Hout,
                                              float* __restrict__ out) {
    // XCD swizzle: 288 blocks = 8 x 36; XCD j gets wids [36j, 36j+36) = 9 row-tiles.
    int flat = blockIdx.x;
    int wid = (flat & 7) * (MAXTILES * 4 / 8) + (flat >> 3);
    int t = wid >> 2;
    if (t >= *ntiles) return;
    int ncol0 = (wid & 3) << 8;
    int e = tile_e[t];
    int sbase = tile_b[t];

    __shared__ ushort As[2][256 * 64];   // 64 KB
    __shared__ ushort Bs[2][256 * 64];   // 64 KB

    int tid = threadIdx.x;
    int wave = tid >> 6, lane = tid & 63, quad = lane >> 4, lm = lane & 15;
    int wm = wave >> 2, wn = wave & 3;

    const ushort* Wte = Wt + (size_t)e * DM * DM;

    int sr = lane >> 3;            // row-in-chunk 0..7
    int gseg = (lane & 7) ^ sr;    // global 16B-seg (xor swizzle keyed on row&7)
    const ushort* aptr[4];         // [h*2+ci]
    const ushort* bptr[4];
    int ldst[4];
#pragma unroll
    for (int h = 0; h < 2; h++)
#pragma unroll
        for (int ci = 0; ci < 2; ci++) {
            int grow = h * 128 + wave * 16 + ci * 8 + sr;
            int ar;
            if (PHASE == 1) {
                ar = slot_token[sbase + grow];
                if (ar < 0) ar = 0;          // pad rows: load row 0, discard in epilogue
            } else {
                ar = sbase + grow;
            }
            aptr[h * 2 + ci] = A + (size_t)ar * DM + gseg * 8;
            bptr[h * 2 + ci] = Wte + (size_t)(ncol0 + grow) * DM + gseg * 8;
            ldst[h * 2 + ci] = (h * 128 + wave * 16 + ci * 8) * 64;
        }

    f32x4 acc[8][4];
#pragma unroll
    for (int i = 0; i < 8; i++)
#pragma unroll
        for (int j = 0; j < 4; j++) acc[i][j] = (f32x4){0.f, 0.f, 0.f, 0.f};

    // fragment LDS offsets (ushort units); ks=1 differs by sel^4 -> idx^32
    int asel = (quad ^ (lm & 7)) * 8;
    int abase = (wm * 128 + lm) * 64 + asel;
    int bbase = (wn * 64 + lm) * 64 + asel;

    bf16x8 af[4][2], bf[4][2];

#define STG_A(buf, h, koff) do { \
        load_lds16(aptr[(h) * 2 + 0] + (koff), &As[(buf)][ldst[(h) * 2 + 0]]); \
        load_lds16(aptr[(h) * 2 + 1] + (koff), &As[(buf)][ldst[(h) * 2 + 1]]); \
    } while (0)
#define STG_B(buf, h, koff) do { \
        load_lds16(bptr[(h) * 2 + 0] + (koff), &Bs[(buf)][ldst[(h) * 2 + 0]]); \
        load_lds16(bptr[(h) * 2 + 1] + (koff), &Bs[(buf)][ldst[(h) * 2 + 1]]); \
    } while (0)
#define LD_AF(Ab, fmb) do { \
        _Pragma("unroll") \
        for (int f = 0; f < 4; f++) { \
            int o = abase + ((fmb) + f) * 1024; \
            af[f][0] = *(const bf16x8*)&(Ab)[o]; \
            af[f][1] = *(const bf16x8*)&(Ab)[o ^ 32]; \
        } \
    } while (0)
#define LD_BF(Bb, fn) do { \
        int o = bbase + (fn) * 1024; \
        bf[fn][0] = *(const bf16x8*)&(Bb)[o]; \
        bf[fn][1] = *(const bf16x8*)&(Bb)[o ^ 32]; \
    } while (0)
#define MM8(fmb, fn) do { \
        _Pragma("unroll") \
        for (int f = 0; f < 4; f++) { \
            acc[(fmb) + f][(fn)] = __builtin_amdgcn_mfma_f32_16x16x32_bf16( \
                af[f][0], bf[(fn)][0], acc[(fmb) + f][(fn)], 0, 0, 0); \
            acc[(fmb) + f][(fn)] = __builtin_amdgcn_mfma_f32_16x16x32_bf16( \
                af[f][1], bf[(fn)][1], acc[(fmb) + f][(fn)], 0, 0, 0); \
        } \
    } while (0)
#define PH_SYNC() do { \
        __builtin_amdgcn_s_barrier(); \
        __builtin_amdgcn_s_waitcnt(0xC07F); /* lgkmcnt(0) */ \
        __builtin_amdgcn_sched_barrier(0); \
    } while (0)
#define PH_END() do { \
        __builtin_amdgcn_sched_barrier(0); \
        __builtin_amdgcn_s_barrier(); \
    } while (0)
#define KTILE(cur, nko, PF) do { \
        const ushort* Ab = &As[(cur)][0]; \
        const ushort* Bb = &Bs[(cur)][0]; \
        /* P0 */ \
        LD_AF(Ab, 0); LD_BF(Bb, 0); LD_BF(Bb, 1); \
        if (PF) STG_B((cur) ^ 1, 0, (nko)); \
        PH_SYNC(); \
        __builtin_amdgcn_s_setprio(1); MM8(0, 0); MM8(0, 1); __builtin_amdgcn_s_setprio(0); \
        PH_END(); \
        /* P1 */ \
        LD_BF(Bb, 2); LD_BF(Bb, 3); \
        if (PF) STG_B((cur) ^ 1, 1, (nko)); \
        PH_SYNC(); \
        __builtin_amdgcn_s_setprio(1); MM8(0, 2); MM8(0, 3); __builtin_amdgcn_s_setprio(0); \
        PH_END(); \
        /* P2 */ \
        LD_AF(Ab, 4); \
        PH_SYNC(); \
        __builtin_amdgcn_s_setprio(1); MM8(4, 0); MM8(4, 1); __builtin_amdgcn_s_setprio(0); \
        PH_END(); \
        /* P3 */ \
        __builtin_amdgcn_s_setprio(1); MM8(4, 2); MM8(4, 3); __builtin_amdgcn_s_setprio(0); \
        __builtin_amdgcn_sched_barrier(0); \
    } while (0)

    // prologue: K-tile 0 fully staged (8 instr in flight)
    STG_A(0, 0, 0); STG_A(0, 1, 0); STG_B(0, 0, 0); STG_B(0, 1, 0);
#pragma unroll 1
    for (int kt = 0; kt < 15; ++kt) {
        int cur = kt & 1;
        int nko = (kt + 1) * 64;
        STG_A(cur ^ 1, 0, nko); STG_A(cur ^ 1, 1, nko);   // 12 outstanding
        __builtin_amdgcn_s_waitcnt(0x0F74);               // vmcnt(4): kt's 8 retired
        __builtin_amdgcn_s_barrier();
        __builtin_amdgcn_sched_barrier(0);
        KTILE(cur, nko, 1);
    }
    // kt = 15: nothing left to prefetch
    __builtin_amdgcn_s_waitcnt(0x0F70);                   // vmcnt(0)
    __builtin_amdgcn_s_barrier();
    __builtin_amdgcn_sched_barrier(0);
    KTILE(1, 0, 0);
#undef STG_A
#undef STG_B
#undef LD_AF
#undef LD_BF
#undef MM8
#undef PH_SYNC
#undef PH_END
#undef KTILE

    // epilogue — C/D layout: col = lane&15, row = quad*4 + r  [m89-verified]
#pragma unroll
    for (int fm = 0; fm < 8; fm++) {
        int rowg = wm * 128 + fm * 16 + quad * 4;
        if (PHASE == 1) {
#pragma unroll
            for (int fn = 0; fn < 4; fn++) {
                int col = ncol0 + wn * 64 + fn * 16 + lm;
                float bv2 = bias[e * DM + col];
#pragma unroll
                for (int r = 0; r < 4; r++) {
                    float v = acc[fm][fn][r] + bv2;
                    v = fmaxf(v, 0.f);
                    Hout[(size_t)(sbase + rowg + r) * DM + col] = f2bf(v);
                }
            }
        } else {
            int tk[4]; float wv[4];
#pragma unroll
            for (int r = 0; r < 4; r++) {
                tk[r] = slot_token[sbase + rowg + r];
                wv[r] = slot_w[sbase + rowg + r];
            }
#pragma unroll
            for (int fn = 0; fn < 4; fn++) {
                int col = ncol0 + wn * 64 + fn * 16 + lm;
                float bv2 = bias[e * DM + col];
#pragma unroll
                for (int r = 0; r < 4; r++) {
                    if (tk[r] >= 0) {
                        float v = wv[r] * (acc[fm][fn][r] + bv2);
                        atomicAdd(&out[(size_t)tk[r] * DM + col], v);
                    }
                }
            }
        }
    }
}

extern "C" void kernel_launch(void* const* d_in, const int* in_sizes, int n_in,
                              void* d_out, int out_size, void* d_ws, size_t ws_size,
                              hipStream_t stream) {
    const float* x  = (const float*)d_in[0];
    const float* Wg = (const float*)d_in[1];
    const float* bg = (const float*)d_in[2];
    const float* W1 = (const float*)d_in[3];
    const float* b1 = (const float*)d_in[4];
    const float* W2 = (const float*)d_in[5];
    const float* b2 = (const float*)d_in[6];
    float* out = (float*)d_out;

    char* ws = (char*)d_ws;
    // workspace layout (bytes) — total ~88.4 MB
    ushort* xb         = (ushort*)(ws + 0);            // 16 MB
    ushort* w1t        = (ushort*)(ws + 16777216);     // 16 MB
    ushort* w2t        = (ushort*)(ws + 33554432);     // 16 MB
    ushort* H          = (ushort*)(ws + 50331648);     // 36 MB (PADCAP*DM*2 = 37748736)
    int*    tok_e      = (int*)  (ws + 88080384);
    float*  tok_w      = (float*)(ws + 88145920);
    int*    slot_token = (int*)  (ws + 88211456);      // PADCAP ints
    float*  slot_w     = (float*)(ws + 88285184);      // PADCAP floats
    int*    counts     = (int*)  (ws + 88358912);
    int*    cursor     = counts + 8;
    int*    tile_e     = counts + 24;
    int*    tile_b     = tile_e + MAXTILES;
    int*    ntiles     = tile_b + MAXTILES;

    dim3 tg(16, 16, 16);
    k_transpose2<<<tg, 256, 0, stream>>>(W1, W2, w1t, w2t, counts);
    k_gate<<<NTOK / 16, 256, 0, stream>>>(x, Wg, bg, xb, tok_e, tok_w, counts,
                                          out, slot_token);
    k_fillplan<<<NTOK / 256, 256, 0, stream>>>(tok_e, tok_w, counts, cursor,
                                               slot_token, slot_w,
                                               tile_e, tile_b, ntiles);

    dim3 gg(4 * MAXTILES);   // 288 blocks, XCD-swizzled in-kernel
    k_gemm<1><<<gg, 512, 0, stream>>>(xb, w1t, b1, slot_token, slot_w,
                                      tile_e, tile_b, ntiles, H, nullptr);
    k_gemm<2><<<gg, 512, 0, stream>>>(H, w2t, b2, slot_token, slot_w,
                                      tile_e, tile_b, ntiles, nullptr, out);
}

// Round 6
// 325.367 us; speedup vs baseline: 1.3499x; 1.3499x over previous
//
#include <hip/hip_runtime.h>
#include <hip/hip_bf16.h>

// MoE top-2, d=1024, E=8, N=8192 tokens. Grouped-GEMM design:
//   gate(top2 + x->bf16 cast + zeroing) -> fillplan -> GEMM1(relu) -> GEMM2(+atomic combine)
// R4-R8: all in-block schedule knobs (depth, BK, phases, conflicts=0, setprio) leave
//   k_gemm at 11-12% MfmaUtil; only TLP/concurrency moved it. R6 gemm = best (113us).
// R9: 128x64 + __launch_bounds__(256,4) occupancy push -> hard crash (unattributed;
//   suspect forced-128-reg spill path). Reverted.
// R10: proven combination, never before run together:
//   - k_gemm: EXACT R6 kernel (3-buf depth-2 pipeline, vmcnt(8), R6 fences, XCD swizzle).
//   - infra: R7's 5-launch fusion (memsets folded into transpose/gate, plan merged in).
//   - fillplan: hierarchical atomics (LDS count -> 8 global atomics/block vs 512);
//     outputs range-proven (n in [0,8192), s < PADCAP).

#define NTOK   8192
#define DM     1024
#define NE     8
#define BM     128
#define NSLOT  (NTOK * 2)
#define PADCAP (NSLOT + NE * BM)      // 17408
#define MAXTILES (PADCAP / BM)        // 136

typedef __attribute__((ext_vector_type(8))) short  bf16x8;
typedef __attribute__((ext_vector_type(4))) float  f32x4;
typedef __attribute__((ext_vector_type(8))) unsigned short u16x8;

__device__ __forceinline__ unsigned short f2bf(float f) {
    union { float f; unsigned u; } v; v.f = f;
    unsigned r = v.u + 0x7fffu + ((v.u >> 16) & 1u);
    return (unsigned short)(r >> 16);
}

// async global->LDS DMA, 16B per lane; dest = wave-uniform base + lane*16
__device__ __forceinline__ void load_lds16(const ushort* g, ushort* l) {
    __builtin_amdgcn_global_load_lds(
        (const __attribute__((address_space(1))) unsigned int*)g,
        (__attribute__((address_space(3))) unsigned int*)l,
        16, 0, 0);
}

// ---------- transpose + cast both weight tensors: Wt[e][n][k] = W[e][k][n] ----------
// Also zeroes counts/cursor (runs first on the stream; k_gate depends on it).
__global__ __launch_bounds__(256) void k_transpose2(const float* __restrict__ W1,
                                                    const float* __restrict__ W2,
                                                    ushort* __restrict__ w1t,
                                                    ushort* __restrict__ w2t,
                                                    int* __restrict__ counts) {
    int tid = threadIdx.x;
    if (blockIdx.x == 0 && blockIdx.y == 0 && blockIdx.z == 0 && tid < 16)
        counts[tid] = 0;   // counts[0..7] + cursor[0..7]
    int ez = blockIdx.z;
    const float* W = (ez < 8 ? W1 : W2) + (size_t)(ez & 7) * DM * DM;
    ushort* Wt = (ez < 8 ? w1t : w2t) + (size_t)(ez & 7) * DM * DM;
    __shared__ float t[64][65];
    int kt = blockIdx.y * 64, nt = blockIdx.x * 64;
    int r16 = tid >> 4, c4 = (tid & 15) * 4;
#pragma unroll
    for (int p = 0; p < 4; p++) {
        int k = p * 16 + r16;
        float4 v = *(const float4*)&W[(size_t)(kt + k) * DM + nt + c4];
        t[k][c4] = v.x; t[k][c4 + 1] = v.y; t[k][c4 + 2] = v.z; t[k][c4 + 3] = v.w;
    }
    __syncthreads();
    int n = tid >> 2, kb = (tid & 3) * 16;
#pragma unroll
    for (int h = 0; h < 2; h++) {
        int k0 = kb + h * 8;
        u16x8 o;
#pragma unroll
        for (int i = 0; i < 8; i++) o[i] = f2bf(t[k0 + i][n]);
        *(u16x8*)&Wt[(size_t)(nt + n) * DM + kt + k0] = o;
    }
}

// ---------- gating: scores = x@Wg + bg (fp32 exact), top-2, counts; casts x->bf16 ----------
// Also zeroes its 16 output rows and its slot_token chunk (replaces memset launches).
__global__ __launch_bounds__(256) void k_gate(const float* __restrict__ x,
                                              const float* __restrict__ Wg,
                                              const float* __restrict__ bg,
                                              ushort* __restrict__ xb,
                                              int* __restrict__ tok_e,
                                              float* __restrict__ tok_w,
                                              int* __restrict__ counts,
                                              float* __restrict__ out,
                                              int* __restrict__ slot_token) {
    __shared__ float wgT[NE][DM];   // 32 KB, transposed: wgT[e][d] = Wg[d][e]
    __shared__ int cnt[NE];
    int tid = threadIdx.x;
    if (tid < NE) cnt[tid] = 0;
    // zero out rows [16*blk, 16*blk+16): 4096 float4 across 256 threads
    {
        float4 z4 = {0.f, 0.f, 0.f, 0.f};
        float4* orow = (float4*)(out + (size_t)blockIdx.x * 16 * DM);
#pragma unroll
        for (int i = 0; i < 16; i++) orow[i * 256 + tid] = z4;
        // slot_token sentinels: PADCAP = 512 blocks * 34
        int s0 = blockIdx.x * (PADCAP / 512);
        for (int i = tid; i < PADCAP / 512; i += 256) slot_token[s0 + i] = -1;
    }
    for (int i = tid; i < DM * NE; i += 256) {
        int d = i >> 3, e = i & 7;
        wgT[e][d] = Wg[i];
    }
    __syncthreads();
    int wave = tid >> 6, lane = tid & 63;
    int n0 = (blockIdx.x * 4 + wave) * 4;
    const float4* xr[4];
#pragma unroll
    for (int t = 0; t < 4; t++) xr[t] = (const float4*)(x + (size_t)(n0 + t) * DM);

    float acc[4][NE];
#pragma unroll
    for (int t = 0; t < 4; t++)
#pragma unroll
        for (int e = 0; e < NE; e++) acc[t][e] = 0.f;

#pragma unroll
    for (int j = 0; j < 4; j++) {
        float4 xv[4];
#pragma unroll
        for (int t = 0; t < 4; t++) xv[t] = xr[t][j * 64 + lane];
#pragma unroll
        for (int t = 0; t < 4; t++) {
            ushort4 o;
            o.x = f2bf(xv[t].x); o.y = f2bf(xv[t].y);
            o.z = f2bf(xv[t].z); o.w = f2bf(xv[t].w);
            ((ushort4*)xb)[(size_t)(n0 + t) * (DM / 4) + j * 64 + lane] = o;
        }
#pragma unroll
        for (int e = 0; e < NE; e++) {
            float4 wv = ((const float4*)&wgT[e][0])[j * 64 + lane];
#pragma unroll
            for (int t = 0; t < 4; t++) {
                acc[t][e] += xv[t].x * wv.x + xv[t].y * wv.y
                           + xv[t].z * wv.z + xv[t].w * wv.w;
            }
        }
    }
#pragma unroll
    for (int t = 0; t < 4; t++)
#pragma unroll
        for (int e = 0; e < NE; e++) {
#pragma unroll
            for (int off = 32; off >= 1; off >>= 1)
                acc[t][e] += __shfl_xor(acc[t][e], off);
        }
    if (lane < 4) {
        int t = lane, n = n0 + t;
        float sc[NE];
#pragma unroll
        for (int e = 0; e < NE; e++) sc[e] = acc[t][e] + bg[e];
        int e0 = 0; float v0 = sc[0];
#pragma unroll
        for (int e = 1; e < NE; e++) if (sc[e] > v0) { v0 = sc[e]; e0 = e; }
        int e1 = -1; float v1 = -3.0e38f;
#pragma unroll
        for (int e = 0; e < NE; e++) if (e != e0 && sc[e] > v1) { v1 = sc[e]; e1 = e; }
        tok_e[2 * n] = e0;     tok_w[2 * n] = v0;
        tok_e[2 * n + 1] = e1; tok_w[2 * n + 1] = v1;
        atomicAdd(&cnt[e0], 1);
        atomicAdd(&cnt[e1], 1);
    }
    __syncthreads();
    if (tid < NE) atomicAdd(&counts[tid], cnt[tid]);
}

// ---------- fill + plan merged, hierarchical atomics ----------
// Per-block LDS counts -> 8 global atomicAdds/block (vs 512) -> local scatter.
// Range-proof: p0/p1 < lcnt[e] <= 256; sum over blocks of lcnt = counts[e];
// s = base[e] + lbase[e] + p < base[e] + counts[e] <= PADCAP.
__global__ __launch_bounds__(256) void k_fillplan(const int* __restrict__ tok_e,
                                                  const float* __restrict__ tok_w,
                                                  const int* __restrict__ counts,
                                                  int* __restrict__ cursor,
                                                  int* __restrict__ slot_token,
                                                  float* __restrict__ slot_w,
                                                  int* __restrict__ tile_e,
                                                  int* __restrict__ tile_b,
                                                  int* __restrict__ ntiles) {
    __shared__ int lcnt[NE], lbase[NE];
    int tid = threadIdx.x;
    if (tid < NE) lcnt[tid] = 0;
    __syncthreads();
    int n = blockIdx.x * 256 + tid;
    int e0 = tok_e[2 * n],     e1 = tok_e[2 * n + 1];
    float w0 = tok_w[2 * n],   w1 = tok_w[2 * n + 1];
    int p0 = atomicAdd(&lcnt[e0], 1);
    int p1 = atomicAdd(&lcnt[e1], 1);
    __syncthreads();
    if (tid < NE) lbase[tid] = atomicAdd(&cursor[tid], lcnt[tid]);
    if (blockIdx.x == 0 && tid == 32) {   // different wave than the cursor atomics
        int t = 0, o2 = 0;
        for (int e = 0; e < NE; e++) {
            int nt = (counts[e] + BM - 1) / BM;
            for (int i = 0; i < nt; i++) { tile_e[t] = e; tile_b[t] = o2 + i * BM; t++; }
            o2 += nt * BM;
        }
        *ntiles = t;
    }
    __syncthreads();
    int base[NE]; int off = 0;
#pragma unroll
    for (int e = 0; e < NE; e++) {
        base[e] = off;
        off += ((counts[e] + BM - 1) / BM) * BM;
    }
    int s0 = base[e0] + lbase[e0] + p0;
    slot_token[s0] = n; slot_w[s0] = w0;
    int s1 = base[e1] + lbase[e1] + p1;
    slot_token[s1] = n; slot_w[s1] = w1;
}

// ---------- grouped GEMM: 128x128 tile, BK=32, 3-buffer async pipeline (R6, verbatim) ----------
// LDS per (buf, operand): [row 0..127][4 seg][8 ushort] = 8 KB; 3 bufs -> 48 KB total.
// DMA chunk = 16 rows x 64B: lane l -> row c*16+(l>>2), LDS seg l&3,
//   GLOBAL seg gseg = (l&3) ^ ((l>>4)&3)  [xor swizzle; dest stays uniform + l*16].
// Element (row, k=g*8+i) at seg_pos = g ^ ((row>>2)&3); fragment-read sel collapses
// to lane-constant quad ^ (lm>>2) -> conflict-free ds_read_b128.
// Pipeline (depth 2): at iter it issue buf (it+2)%3, s_waitcnt vmcnt(8) -> only the
// oldest 4 (= current buf) must land; 8 newer DMAs stay in flight across barriers.
// FENCES (R6): sched_barrier(0) pins ds_read/MFMA strictly between the barriers;
// lgkmcnt(0) before the end barrier guarantees ds_reads retired before republish.
// Grid is 1-D, XCD-swizzled: XCD j gets tiles [17j, 17j+17) x all 8 col-tiles, i.e.
// ~one expert -> its 2MB weight panel + A rows are L2-resident on that XCD.
template <int PHASE>
__global__ __launch_bounds__(256) void k_gemm(const ushort* __restrict__ A,
                                              const ushort* __restrict__ Wt,
                                              const float* __restrict__ bias,
                                              const int* __restrict__ slot_token,
                                              const float* __restrict__ slot_w,
                                              const int* __restrict__ tile_e,
                                              const int* __restrict__ tile_b,
                                              const int* __restrict__ ntiles,
                                              ushort* __restrict__ Hout,
                                              float* __restrict__ out) {
    // XCD-aware swizzle: nblocks = 8*MAXTILES (divisible by 8); chunk = MAXTILES.
    int flat = blockIdx.x;
    int wid = (flat & 7) * MAXTILES + (flat >> 3);
    int t = wid >> 3;
    if (t >= *ntiles) return;
    int ncol0 = (wid & 7) << 7;
    int e = tile_e[t];
    int sbase = tile_b[t];

    __shared__ ushort As[3][4096];   // [buf][row*32 + segpos*8]
    __shared__ ushort Bs[3][4096];

    int tid = threadIdx.x;
    int wave = tid >> 6, lane = tid & 63, quad = lane >> 4, lm = lane & 15;
    int wm = wave >> 1, wn = wave & 1;

    const ushort* Wte = Wt + (size_t)e * DM * DM;

    // staging: wave w covers chunks {2w, 2w+1} per operand (16 rows each)
    int sr = lane >> 2;                            // row-in-chunk 0..15
    int gseg = (lane & 3) ^ ((lane >> 4) & 3);     // global 16B-seg (xor swizzle)
    const ushort* aptr[2];
    const ushort* bptr[2];
#pragma unroll
    for (int ci = 0; ci < 2; ci++) {
        int row = (wave * 2 + ci) * 16 + sr;
        int ar;
        if (PHASE == 1) {
            ar = slot_token[sbase + row];
            if (ar < 0) ar = 0;              // pad rows: load row 0, discard in epilogue
        } else {
            ar = sbase + row;
        }
        aptr[ci] = A + (size_t)ar * DM + gseg * 8;
        bptr[ci] = Wte + (size_t)(ncol0 + row) * DM + gseg * 8;
    }

    f32x4 acc[4][4];
#pragma unroll
    for (int i = 0; i < 4; i++)
#pragma unroll
        for (int j = 0; j < 4; j++) acc[i][j] = (f32x4){0.f, 0.f, 0.f, 0.f};

    // fragment LDS offsets (ushort units): lane-constant swizzle sel
    int asel = ((quad ^ (lm >> 2)) & 3) * 8;
    int abase = (wm * 64 + lm) * 32 + asel;
    int bbase = (wn * 64 + lm) * 32 + asel;

#define ISSUE(buf, koff)                                          \
    do {                                                          \
        _Pragma("unroll")                                         \
        for (int ci = 0; ci < 2; ci++) {                          \
            int cb = (wave * 2 + ci) * 512;                       \
            load_lds16(aptr[ci] + (koff), &As[(buf)][cb]);        \
            load_lds16(bptr[ci] + (koff), &Bs[(buf)][cb]);        \
        }                                                         \
    } while (0)

#define COMPUTE(buf)                                                          \
    do {                                                                      \
        const ushort* Ab = As[(buf)];                                         \
        const ushort* Bb = Bs[(buf)];                                         \
        bf16x8 av[4], bv[4];                                                  \
        _Pragma("unroll")                                                     \
        for (int f = 0; f < 4; f++) {                                         \
            av[f] = *(const bf16x8*)&Ab[abase + f * 512];                     \
            bv[f] = *(const bf16x8*)&Bb[bbase + f * 512];                     \
        }                                                                     \
        _Pragma("unroll")                                                     \
        for (int fm = 0; fm < 4; fm++)                                        \
            _Pragma("unroll")                                                 \
            for (int fn = 0; fn < 4; fn++)                                    \
                acc[fm][fn] = __builtin_amdgcn_mfma_f32_16x16x32_bf16(        \
                    av[fm], bv[fn], acc[fm][fn], 0, 0, 0);                    \
    } while (0)

    // prologue: bufs 0 and 1 in flight (8 outstanding DMAs/wave)
    ISSUE(0, 0);
    ISSUE(1, 32);
#pragma unroll 3
    for (int it = 0; it < 30; ++it) {
        ISSUE((it + 2) % 3, (it + 2) * 32);       // 12 outstanding
        __builtin_amdgcn_s_waitcnt(0x0F78);       // vmcnt(8): current buf landed
        __builtin_amdgcn_s_barrier();
        __builtin_amdgcn_sched_barrier(0);        // ds_reads may not hoist above
        COMPUTE(it % 3);
        __builtin_amdgcn_sched_barrier(0);        // MFMAs/ds_reads may not sink below
        __builtin_amdgcn_s_waitcnt(0xC07F);       // lgkmcnt(0): ds_reads retired
        __builtin_amdgcn_s_barrier();             // readers done before buf re-staged
    }
    // it = 30: bufs 30,31 outstanding
    __builtin_amdgcn_s_waitcnt(0x0F74);           // vmcnt(4): buf 30 landed
    __builtin_amdgcn_s_barrier();
    __builtin_amdgcn_sched_barrier(0);
    COMPUTE(0);                                   // 30 % 3
    __builtin_amdgcn_sched_barrier(0);
    __builtin_amdgcn_s_waitcnt(0xC07F);
    __builtin_amdgcn_s_barrier();
    // it = 31
    __builtin_amdgcn_s_waitcnt(0x0F70);           // vmcnt(0): buf 31 landed
    __builtin_amdgcn_s_barrier();
    __builtin_amdgcn_sched_barrier(0);
    COMPUTE(1);                                   // 31 % 3
#undef ISSUE
#undef COMPUTE

    // epilogue — C/D layout: col = lane&15, row = quad*4 + r  [m89-verified]
#pragma unroll
    for (int fm = 0; fm < 4; fm++) {
        int rowg = wm * 64 + fm * 16 + quad * 4;
        if (PHASE == 1) {
#pragma unroll
            for (int fn = 0; fn < 4; fn++) {
                int col = ncol0 + wn * 64 + fn * 16 + lm;
                float bv2 = bias[e * DM + col];
#pragma unroll
                for (int r = 0; r < 4; r++) {
                    float v = acc[fm][fn][r] + bv2;
                    v = fmaxf(v, 0.f);
                    Hout[(size_t)(sbase + rowg + r) * DM + col] = f2bf(v);
                }
            }
        } else {
            int tk[4]; float wv[4];
#pragma unroll
            for (int r = 0; r < 4; r++) {
                tk[r] = slot_token[sbase + rowg + r];
                wv[r] = slot_w[sbase + rowg + r];
            }
#pragma unroll
            for (int fn = 0; fn < 4; fn++) {
                int col = ncol0 + wn * 64 + fn * 16 + lm;
                float bv2 = bias[e * DM + col];
#pragma unroll
                for (int r = 0; r < 4; r++) {
                    if (tk[r] >= 0) {
                        float v = wv[r] * (acc[fm][fn][r] + bv2);
                        atomicAdd(&out[(size_t)tk[r] * DM + col], v);
                    }
                }
            }
        }
    }
}

extern "C" void kernel_launch(void* const* d_in, const int* in_sizes, int n_in,
                              void* d_out, int out_size, void* d_ws, size_t ws_size,
                              hipStream_t stream) {
    const float* x  = (const float*)d_in[0];
    const float* Wg = (const float*)d_in[1];
    const float* bg = (const float*)d_in[2];
    const float* W1 = (const float*)d_in[3];
    const float* b1 = (const float*)d_in[4];
    const float* W2 = (const float*)d_in[5];
    const float* b2 = (const float*)d_in[6];
    float* out = (float*)d_out;

    char* ws = (char*)d_ws;
    // workspace layout (bytes) — total ~86.3 MB
    ushort* xb         = (ushort*)(ws + 0);            // 16 MB
    ushort* w1t        = (ushort*)(ws + 16777216);     // 16 MB
    ushort* w2t        = (ushort*)(ws + 33554432);     // 16 MB
    ushort* H          = (ushort*)(ws + 50331648);     // 34 MB (PADCAP*DM*2)
    int*    tok_e      = (int*)  (ws + 85983232);
    float*  tok_w      = (float*)(ws + 86048768);
    int*    slot_token = (int*)  (ws + 86114304);
    float*  slot_w     = (float*)(ws + 86183936);
    int*    counts     = (int*)  (ws + 86253568);
    int*    cursor     = counts + 8;
    int*    tile_e     = counts + 24;
    int*    tile_b     = tile_e + MAXTILES;
    int*    ntiles     = tile_b + MAXTILES;

    dim3 tg(16, 16, 16);
    k_transpose2<<<tg, 256, 0, stream>>>(W1, W2, w1t, w2t, counts);
    k_gate<<<NTOK / 16, 256, 0, stream>>>(x, Wg, bg, xb, tok_e, tok_w, counts,
                                          out, slot_token);
    k_fillplan<<<NTOK / 256, 256, 0, stream>>>(tok_e, tok_w, counts, cursor,
                                               slot_token, slot_w,
                                               tile_e, tile_b, ntiles);

    dim3 gg(8 * MAXTILES);   // 1088 blocks, XCD-swizzled in-kernel
    k_gemm<1><<<gg, 256, 0, stream>>>(xb, w1t, b1, slot_token, slot_w,
                                      tile_e, tile_b, ntiles, H, nullptr);
    k_gemm<2><<<gg, 256, 0, stream>>>(H, w2t, b2, slot_token, slot_w,
                                      tile_e, tile_b, ntiles, nullptr, out);
}